// Round 3
// baseline (582.366 us; speedup 1.0000x reference)
//
#include <hip/hip_runtime.h>

#define NB 4
#define P 1024
#define ITERS 50
#define WPB 64            // workgroups per batch (main kernel)
#define THREADS 256
#define K_COEF (-14.426950408889634f)  // -log2(e)/eps, eps=0.1
#define DELTA 1e-8f

typedef unsigned long long u64;
typedef unsigned int u32;

// ws layout: [0,32KB) a_t[NB][P] u64 (tag<<32|float) | [32KB,64KB) b_t[NB][P] u64

__global__ void sink_zero(u64* ab, float* out) {
    int t = blockIdx.x * blockDim.x + threadIdx.x;
    if (t < 2 * NB * P) ab[t] = 0ull;
    if (t < NB) out[t] = 0.0f;
}

// Poll-read 16 tagged words g[l+64k]; returns floats once all tags == tag.
// All 16 loads issue before any check (single waitcnt); re-poll only laggards.
__device__ __forceinline__ void poll_vec(const u64* __restrict__ g, int l, u32 tag,
                                         float* dst) {
    u64 v[16];
    #pragma unroll
    for (int k = 0; k < 16; ++k)
        v[k] = __hip_atomic_load(&g[l + 64 * k], __ATOMIC_RELAXED,
                                 __HIP_MEMORY_SCOPE_AGENT);
    for (;;) {
        bool all = true;
        #pragma unroll
        for (int k = 0; k < 16; ++k) all &= ((u32)(v[k] >> 32) == tag);
        if (all) break;
        __builtin_amdgcn_s_sleep(1);
        #pragma unroll
        for (int k = 0; k < 16; ++k)
            if ((u32)(v[k] >> 32) != tag)
                v[k] = __hip_atomic_load(&g[l + 64 * k], __ATOMIC_RELAXED,
                                         __HIP_MEMORY_SCOPE_AGENT);
    }
    #pragma unroll
    for (int k = 0; k < 16; ++k) dst[k] = __uint_as_float((u32)v[k]);
}

__device__ __forceinline__ u64 pack(u32 tag, float x) {
    return ((u64)tag << 32) | (u64)__float_as_uint(x);
}

__global__ __launch_bounds__(THREADS, 1)
void sink_main(const float* __restrict__ mu, const float* __restrict__ nu,
               const float* __restrict__ C,
               u64* __restrict__ a_t, u64* __restrict__ b_t) {
    const int n   = blockIdx.x >> 6;   // batch
    const int w   = blockIdx.x & 63;   // wg within batch
    const int tid = threadIdx.x;
    const int wq  = tid >> 6;          // wave id 0..3
    const int l   = tid & 63;          // lane

    u64* a_g = a_t + n * P;
    u64* b_g = b_t + n * P;
    const float* Cb = C + (size_t)n * P * P;
    const int base = w * 16 + 4 * wq;  // this wave's first row (and col)

    float Kr[4][16], Kt[4][16], muv[4], nuv[4];

    // Kr[q][k] = K[base+q][l+64k]  (each scalar load wave-coalesced 256B)
    #pragma unroll
    for (int q = 0; q < 4; ++q) {
        const int r = base + q;
        #pragma unroll
        for (int k = 0; k < 16; ++k)
            Kr[q][k] = exp2f(K_COEF * Cb[(size_t)r * P + l + 64 * k]);
        muv[q] = mu[n * P + r] + DELTA;
        nuv[q] = nu[n * P + r] + DELTA;
    }
    // Kt[q][k] = K[l+64k][base+q]  (float4 over the wave's 4 contiguous cols)
    #pragma unroll
    for (int k = 0; k < 16; ++k) {
        const float4 c4 = *reinterpret_cast<const float4*>(
            Cb + (size_t)(l + 64 * k) * P + base);
        Kt[0][k] = exp2f(K_COEF * c4.x);
        Kt[1][k] = exp2f(K_COEF * c4.y);
        Kt[2][k] = exp2f(K_COEF * c4.z);
        Kt[3][k] = exp2f(K_COEF * c4.w);
    }

    float b_r[16], a_r[16], a_own[4];
    #pragma unroll
    for (int k = 0; k < 16; ++k) b_r[k] = 1.0f;   // v=0 -> b=1

    for (int t = 0; t < ITERS; ++t) {
        if (t) poll_vec(b_g, l, (u32)t, b_r);     // b tagged t
        // phase A: a_i = (mu_i+d) / sum_j K_ij b_j ; publish tag t+1
        #pragma unroll
        for (int q = 0; q < 4; ++q) {
            float y = 0.f;
            #pragma unroll
            for (int k = 0; k < 16; ++k) y += Kr[q][k] * b_r[k];
            #pragma unroll
            for (int off = 32; off > 0; off >>= 1) y += __shfl_xor(y, off, 64);
            a_own[q] = muv[q] / y;
        }
        if (l == 0) {
            #pragma unroll
            for (int q = 0; q < 4; ++q)
                __hip_atomic_store(&a_g[base + q], pack((u32)(t + 1), a_own[q]),
                                   __ATOMIC_RELAXED, __HIP_MEMORY_SCOPE_AGENT);
        }
        // phase B: b_j = (nu_j+d) / sum_i K_ij a_i ; publish tag t+1
        poll_vec(a_g, l, (u32)(t + 1), a_r);
        #pragma unroll
        for (int q = 0; q < 4; ++q) {
            float y = 0.f;
            #pragma unroll
            for (int k = 0; k < 16; ++k) y += Kt[q][k] * a_r[k];
            #pragma unroll
            for (int off = 32; off > 0; off >>= 1) y += __shfl_xor(y, off, 64);
            if (l == 0)
                __hip_atomic_store(&b_g[base + q], pack((u32)(t + 1), nuv[q] / y),
                                   __ATOMIC_RELAXED, __HIP_MEMORY_SCOPE_AGENT);
        }
    }
    // final a,b (tag 50) visible to sink_epi via kernel-boundary coherence
}

// epilogue: pi = a_i K_ij b_j ; cost = sum pi*C ; copy C through
__global__ __launch_bounds__(256)
void sink_epi(const float* __restrict__ C, const u64* __restrict__ a_t,
              const u64* __restrict__ b_t, float* __restrict__ out) {
    const int tid = threadIdx.x;
    const size_t f = ((size_t)blockIdx.x * 256 + tid) * 4;
    const int n  = (int)(f >> 20);
    const int r  = (int)((f >> 10) & 1023);
    const int j0 = (int)(f & 1023);

    const float a = __uint_as_float((u32)a_t[n * P + r]);
    const u64* bg = b_t + n * P;
    const float b0 = __uint_as_float((u32)bg[j0 + 0]);
    const float b1 = __uint_as_float((u32)bg[j0 + 1]);
    const float b2 = __uint_as_float((u32)bg[j0 + 2]);
    const float b3 = __uint_as_float((u32)bg[j0 + 3]);

    const float4 c4 = *reinterpret_cast<const float4*>(C + f);
    float4 p4;
    p4.x = a * exp2f(K_COEF * c4.x) * b0;
    p4.y = a * exp2f(K_COEF * c4.y) * b1;
    p4.z = a * exp2f(K_COEF * c4.z) * b2;
    p4.w = a * exp2f(K_COEF * c4.w) * b3;

    float* out_pi = out + 4;
    float* out_C  = out + 4 + (size_t)NB * P * P;
    *reinterpret_cast<float4*>(out_pi + f) = p4;
    *reinterpret_cast<float4*>(out_C + f)  = c4;

    float costp = p4.x * c4.x + p4.y * c4.y + p4.z * c4.z + p4.w * c4.w;
    #pragma unroll
    for (int off = 32; off > 0; off >>= 1) costp += __shfl_xor(costp, off, 64);
    __shared__ float reds[4];
    if ((tid & 63) == 0) reds[tid >> 6] = costp;
    __syncthreads();
    if (tid == 0) atomicAdd(&out[n], reds[0] + reds[1] + reds[2] + reds[3]);
}

extern "C" void kernel_launch(void* const* d_in, const int* in_sizes, int n_in,
                              void* d_out, int out_size, void* d_ws, size_t ws_size,
                              hipStream_t stream) {
    const float* mu = (const float*)d_in[0];
    const float* nu = (const float*)d_in[1];
    const float* C  = (const float*)d_in[2];
    float* out = (float*)d_out;
    u64* a_t = (u64*)d_ws;                 // [0,32KB)
    u64* b_t = a_t + NB * P;               // [32KB,64KB)

    sink_zero<<<32, 256, 0, stream>>>(a_t, out);
    sink_main<<<NB * WPB, THREADS, 0, stream>>>(mu, nu, C, a_t, b_t);
    sink_epi<<<(NB * P * P) / (256 * 4), 256, 0, stream>>>(C, a_t, b_t, out);
}

// Round 4
// 257.978 us; speedup vs baseline: 2.2574x; 2.2574x over previous
//
#include <hip/hip_runtime.h>

#define NB 4
#define P 1024
#define ITERS 50
#define WPB 64            // workgroups per batch
#define THREADS 256
#define K_COEF (-14.426950408889634f)  // -log2(e)/eps, eps=0.1
#define DELTA 1e-8f

typedef unsigned int u32;

// ws layout: [0, 800KB) z[NB][ITERS][P] f32 | [800KB, +1KB) cnt[NB][ITERS] u32

__global__ void sink_zero(float* z, u32* cnt, float* out) {
    int t = blockIdx.x * blockDim.x + threadIdx.x;
    if (t < NB * ITERS * P) z[t] = 0.0f;
    if (t < NB * ITERS) cnt[t] = 0;
    if (t < NB) out[t] = 0.0f;
}

__global__ __launch_bounds__(THREADS, 1)
void sink_main(const float* __restrict__ mu, const float* __restrict__ nu,
               const float* __restrict__ C, float* __restrict__ out,
               float* __restrict__ z, u32* __restrict__ cnt) {
    const int n   = blockIdx.x >> 6;   // batch
    const int w   = blockIdx.x & 63;   // wg within batch
    const int tid = threadIdx.x;
    const int wq  = tid >> 6;          // wave 0..3
    const int l   = tid & 63;          // lane

    float* zb = z + (size_t)n * ITERS * P;
    u32*   cb = cnt + n * ITERS;
    const float* Cb = C + (size_t)n * P * P;
    const int base = w * 16 + 4 * wq;  // this wave's first row

    float Kr[4][16], muv[4], nur[16], b_r[16], a_own[4];

    // Kr[q][k] = K[base+q][l+64k]  (each load: 64 lanes x 4B = 256B coalesced)
    #pragma unroll
    for (int q = 0; q < 4; ++q) {
        const int r = base + q;
        #pragma unroll
        for (int k = 0; k < 16; ++k)
            Kr[q][k] = exp2f(K_COEF * Cb[(size_t)r * P + l + 64 * k]);
        muv[q] = mu[n * P + r] + DELTA;
    }
    #pragma unroll
    for (int k = 0; k < 16; ++k) nur[k] = nu[n * P + l + 64 * k] + DELTA;
    #pragma unroll
    for (int k = 0; k < 16; ++k) b_r[k] = 1.0f;   // v=0 -> b=1

    __shared__ float zs[4][P];   // 16KB: per-wave column partials

    for (int t = 0; t < ITERS; ++t) {
        if (t) {
            // wait for z[t-1] complete (64 arrivals), then b = nu / z[t-1]
            if (tid == 0)
                while (__hip_atomic_load(&cb[t - 1], __ATOMIC_RELAXED,
                                         __HIP_MEMORY_SCOPE_AGENT) < WPB) {}
            __syncthreads();
            const float* zt = zb + (size_t)(t - 1) * P;
            #pragma unroll
            for (int k = 0; k < 16; ++k) {
                float zv = __hip_atomic_load(&zt[l + 64 * k], __ATOMIC_RELAXED,
                                             __HIP_MEMORY_SCOPE_AGENT);
                b_r[k] = nur[k] / zv;
            }
        }
        // a_i = (mu_i+d) / sum_j K_ij b_j   (own rows, never published)
        #pragma unroll
        for (int q = 0; q < 4; ++q) {
            float y = 0.f;
            #pragma unroll
            for (int k = 0; k < 16; ++k) y += Kr[q][k] * b_r[k];
            #pragma unroll
            for (int off = 32; off > 0; off >>= 1) y += __shfl_xor(y, off, 64);
            a_own[q] = muv[q] / y;
        }
        // column partials: zs[wq][l+64k] = sum_q Kr[q][k] * a_own[q]
        #pragma unroll
        for (int k = 0; k < 16; ++k) {
            float s = Kr[0][k] * a_own[0] + Kr[1][k] * a_own[1]
                    + Kr[2][k] * a_own[2] + Kr[3][k] * a_own[3];
            zs[wq][l + 64 * k] = s;
        }
        __syncthreads();
        // WG-level reduce (4 waves) + one device atomicAdd per column
        {
            float* zt = zb + (size_t)t * P;
            #pragma unroll
            for (int g = 0; g < 4; ++g) {
                const int j = tid + 256 * g;
                atomicAdd(&zt[j], zs[0][j] + zs[1][j] + zs[2][j] + zs[3][j]);
            }
        }
        __syncthreads();   // each wave: s_waitcnt vmcnt(0) -> its adds are acked
        if (tid == 0)
            __hip_atomic_fetch_add(&cb[t], 1u, __ATOMIC_RELAXED,
                                   __HIP_MEMORY_SCOPE_AGENT);
    }

    // final b^{(50)} = nu / z[49]
    if (tid == 0)
        while (__hip_atomic_load(&cb[ITERS - 1], __ATOMIC_RELAXED,
                                 __HIP_MEMORY_SCOPE_AGENT) < WPB) {}
    __syncthreads();
    {
        const float* zt = zb + (size_t)(ITERS - 1) * P;
        #pragma unroll
        for (int k = 0; k < 16; ++k) {
            float zv = __hip_atomic_load(&zt[l + 64 * k], __ATOMIC_RELAXED,
                                         __HIP_MEMORY_SCOPE_AGENT);
            b_r[k] = nur[k] / zv;
        }
    }

    // fused epilogue: pi = a_i K_ij b_j ; cost = sum pi*C ; copy C through
    float* out_pi = out + 4;
    float* out_C  = out + 4 + (size_t)NB * P * P;
    float costp = 0.f;
    #pragma unroll
    for (int q = 0; q < 4; ++q) {
        const int r = base + q;
        const size_t rowoff = (size_t)n * P * P + (size_t)r * P;
        #pragma unroll
        for (int k = 0; k < 16; ++k) {
            const int j = l + 64 * k;
            const float c = Cb[(size_t)r * P + j];
            const float p = a_own[q] * Kr[q][k] * b_r[k];
            out_pi[rowoff + j] = p;
            out_C[rowoff + j]  = c;
            costp += p * c;
        }
    }
    #pragma unroll
    for (int off = 32; off > 0; off >>= 1) costp += __shfl_xor(costp, off, 64);
    if (l == 0) zs[0][wq] = costp;
    __syncthreads();
    if (tid == 0) atomicAdd(&out[n], zs[0][0] + zs[0][1] + zs[0][2] + zs[0][3]);
}

extern "C" void kernel_launch(void* const* d_in, const int* in_sizes, int n_in,
                              void* d_out, int out_size, void* d_ws, size_t ws_size,
                              hipStream_t stream) {
    const float* mu = (const float*)d_in[0];
    const float* nu = (const float*)d_in[1];
    const float* C  = (const float*)d_in[2];
    float* out = (float*)d_out;
    float* zws = (float*)d_ws;                                   // 800KB
    u32*   cnt = (u32*)((char*)d_ws + NB * ITERS * P * sizeof(float));

    sink_zero<<<(NB * ITERS * P + 1023) / 1024, 1024, 0, stream>>>(zws, cnt, out);
    sink_main<<<NB * WPB, THREADS, 0, stream>>>(mu, nu, C, out, zws, cnt);
}

// Round 5
// 221.725 us; speedup vs baseline: 2.6265x; 1.1635x over previous
//
#include <hip/hip_runtime.h>

#define NB 4
#define P 1024
#define ITERS 50
#define WPB 16              // workgroups per batch
#define THREADS 1024
#define WAVES 16
#define K_COEF (-14.426950408889634f)  // -log2(e)/eps, eps=0.1
#define DELTA 1e-8f
#define SCALE 274877906944.0f          // 2^38 fixed-point scale
#define M56 0x00FFFFFFFFFFFFFFull
#define CNT_ONE (1ull << 56)

typedef unsigned long long u64;
typedef unsigned int u32;

// ws layout: [0, 1.6MB) z[NB][ITERS][P] u64 : (arrivals<<56) | fixed-point sum

__global__ void sink_zero(u64* z, float* out) {
    size_t t = (size_t)blockIdx.x * 1024 + threadIdx.x;
    if (t < (size_t)NB * ITERS * P) z[t] = 0ull;
    if (t < NB) out[t] = 0.0f;
}

__global__ __launch_bounds__(THREADS, 4)
void sink_main(const float* __restrict__ mu, const float* __restrict__ nu,
               const float* __restrict__ C, float* __restrict__ out,
               u64* __restrict__ z) {
    const int n   = blockIdx.x >> 4;   // batch
    const int w   = blockIdx.x & 15;   // wg within batch
    const int tid = threadIdx.x;
    const int wq  = tid >> 6;          // wave 0..15
    const int l   = tid & 63;          // lane

    u64* zb = z + (size_t)n * ITERS * P;
    const float* Cb = C + (size_t)n * P * P;
    const int base = w * 64 + wq * 4;  // this wave's first row

    float Kr[4][16], muv[4], b_r[16], a_own[4];

    // Kr[q][k] = K[base+q][l+64k]  (each load: 64 lanes x 4B = 256B coalesced)
    #pragma unroll
    for (int q = 0; q < 4; ++q) {
        const int r = base + q;
        #pragma unroll
        for (int k = 0; k < 16; ++k)
            Kr[q][k] = exp2f(K_COEF * Cb[(size_t)r * P + l + 64 * k]);
        muv[q] = mu[n * P + r] + DELTA;
    }
    // this thread's own column = tid
    const float nuv_s = (nu[n * P + tid] + DELTA) * SCALE;

    __shared__ float bs[P];            // 4KB  : broadcast b
    __shared__ float zs[WAVES][P];     // 64KB : per-wave column partials

    #pragma unroll
    for (int k = 0; k < 16; ++k) b_r[k] = 1.0f;   // v=0 -> b=1

    for (int t = 0; t < ITERS; ++t) {
        // a_i = (mu_i+d) / sum_j K_ij b_j   (own rows, never published)
        #pragma unroll
        for (int q = 0; q < 4; ++q) {
            float y = 0.f;
            #pragma unroll
            for (int k = 0; k < 16; ++k) y += Kr[q][k] * b_r[k];
            #pragma unroll
            for (int off = 32; off > 0; off >>= 1) y += __shfl_xor(y, off, 64);
            a_own[q] = muv[q] / y;
        }
        // per-wave column partials
        #pragma unroll
        for (int k = 0; k < 16; ++k)
            zs[wq][l + 64 * k] = Kr[0][k] * a_own[0] + Kr[1][k] * a_own[1]
                               + Kr[2][k] * a_own[2] + Kr[3][k] * a_own[3];
        __syncthreads();
        // WG reduce (16 waves) -> ONE tagged fixed-point RMW per column per WG
        float red = 0.f;
        #pragma unroll
        for (int g = 0; g < WAVES; ++g) red += zs[g][tid];
        u64* zt = zb + (size_t)t * P;
        const u64 own = CNT_ONE + (u64)(red * SCALE);
        u64 v = __hip_atomic_fetch_add(&zt[tid], own, __ATOMIC_RELAXED,
                                       __HIP_MEMORY_SCOPE_AGENT) + own;
        // poll own column word: count in top byte, sum in low 56 bits
        while ((v >> 56) != (u64)WPB) {
            __builtin_amdgcn_s_sleep(1);
            v = __hip_atomic_load(&zt[tid], __ATOMIC_RELAXED,
                                  __HIP_MEMORY_SCOPE_AGENT);
        }
        bs[tid] = nuv_s / (float)(v & M56);   // b_j = nu_j / z_j
        __syncthreads();
        #pragma unroll
        for (int k = 0; k < 16; ++k) b_r[k] = bs[l + 64 * k];
        // NOTE: no further barrier needed — poll-pass at t+1 transitively
        // implies every thread of every WG passed this iteration's barriers.
    }

    // fused epilogue: pi = a_i K_ij b_j ; cost = sum pi*C ; copy C through
    float* out_pi = out + 4;
    float* out_C  = out + 4 + (size_t)NB * P * P;
    float costp = 0.f;
    #pragma unroll
    for (int q = 0; q < 4; ++q) {
        const int r = base + q;
        const size_t rowoff = (size_t)n * P * P + (size_t)r * P;
        #pragma unroll
        for (int k = 0; k < 16; ++k) {
            const int j = l + 64 * k;
            const float c = Cb[(size_t)r * P + j];
            const float p = a_own[q] * Kr[q][k] * b_r[k];
            out_pi[rowoff + j] = p;
            out_C[rowoff + j]  = c;
            costp += p * c;
        }
    }
    #pragma unroll
    for (int off = 32; off > 0; off >>= 1) costp += __shfl_xor(costp, off, 64);
    __syncthreads();               // bs free for reuse
    if (l == 0) bs[wq] = costp;
    __syncthreads();
    if (tid == 0) {
        float s = 0.f;
        #pragma unroll
        for (int g = 0; g < WAVES; ++g) s += bs[g];
        atomicAdd(&out[n], s);
    }
}

extern "C" void kernel_launch(void* const* d_in, const int* in_sizes, int n_in,
                              void* d_out, int out_size, void* d_ws, size_t ws_size,
                              hipStream_t stream) {
    const float* mu = (const float*)d_in[0];
    const float* nu = (const float*)d_in[1];
    const float* C  = (const float*)d_in[2];
    float* out = (float*)d_out;
    u64* zws = (u64*)d_ws;   // NB*ITERS*P*8 = 1.6 MB

    sink_zero<<<(NB * ITERS * P + 1023) / 1024, 1024, 0, stream>>>(zws, out);
    sink_main<<<NB * WPB, THREADS, 0, stream>>>(mu, nu, C, out, zws);
}